// Round 3
// baseline (54.850 us; speedup 1.0000x reference)
//
#include <hip/hip_runtime.h>
#include <math.h>

#define NN 1024
#define DIN 6
#define DI 16
#define DE 64
#define GC 4              // centres per block
#define NT 512            // threads per centre-block
#define NWAVE (NT/64)     // 8
#define NBLK (NN/GC)      // 256

// ws layout (floats)
#define OFF_QI 0
#define OFF_KI (OFF_QI + NN*DI)
#define OFF_QE (OFF_KI + NN*DI)
#define OFF_KR (OFF_QE + NN*DE)
#define OFF_KV (OFF_KR + NN*DE)
#define OFF_VR (OFF_KV + NN*DE)
#define OFF_VV (OFF_VR + NN*DE)
#define OFF_GR (OFF_VV + NN*DE)
#define OFF_GV (OFF_GR + NN)

__global__ __launch_bounds__(256) void nce_precompute(
    const float* __restrict__ nc,
    const float* __restrict__ Wq_i, const float* __restrict__ Wk_i,
    const float* __restrict__ Wv_i, const float* __restrict__ Wq_e,
    const float* __restrict__ Wk_e, const float* __restrict__ Wv_e,
    const float* __restrict__ wg, float* __restrict__ ws)
{
    const int s    = threadIdx.x >> 6;     // node sub-index within block
    const int lane = threadIdx.x & 63;     // = encoding dim d
    const int n    = blockIdx.x * 4 + s;
    __shared__ float s_vi[4][DI];

    float x[DIN];
    #pragma unroll
    for (int f = 0; f < DIN; ++f) x[f] = nc[n*DIN + f];

    if (lane < DI) {
        float qi = 0.f, ki = 0.f, vv = 0.f;
        #pragma unroll
        for (int f = 0; f < DIN; ++f) {
            qi += x[f] * Wq_i[f*DI + lane];
            ki += x[f] * Wk_i[f*DI + lane];
            vv += x[f] * Wv_i[f*DI + lane];
        }
        ws[OFF_QI + n*DI + lane] = qi;
        ws[OFF_KI + n*DI + lane] = ki;
        s_vi[s][lane] = vv;
    }
    __syncthreads();

    float qe = 0.f, kr = 0.f, vr = 0.f;
    #pragma unroll
    for (int f = 0; f < DIN; ++f) {
        qe += x[f] * Wq_e[f*DE + lane];
        kr += x[f] * Wk_e[f*DE + lane];
        vr += x[f] * Wv_e[f*DE + lane];
    }
    float kv = 0.f, vv2 = 0.f;
    #pragma unroll
    for (int j = 0; j < DI; ++j) {
        float v = s_vi[s][j];
        kv  += v * Wk_e[(DIN+j)*DE + lane];
        vv2 += v * Wv_e[(DIN+j)*DE + lane];
    }
    ws[OFF_QE + n*DE + lane] = qe;
    ws[OFF_KR + n*DE + lane] = kr;
    ws[OFF_KV + n*DE + lane] = kv;
    ws[OFF_VR + n*DE + lane] = vr;
    ws[OFF_VV + n*DE + lane] = vv2;

    float w   = wg[lane];
    float grt = vr * w, gvt = vv2 * w;
    #pragma unroll
    for (int off = 32; off > 0; off >>= 1) {
        grt += __shfl_xor(grt, off, 64);
        gvt += __shfl_xor(gvt, off, 64);
    }
    if (lane == 0) { ws[OFF_GR + n] = grt; ws[OFF_GV + n] = gvt; }
}

__device__ __forceinline__ float dot4(float4 a, float4 b) {
    return a.x*b.x + a.y*b.y + a.z*b.z + a.w*b.w;
}

template<bool IS_MAX>
__device__ __forceinline__ void blk_red(float v[GC], float (*s_red)[NWAVE],
                                        int wave, int lane)
{
    #pragma unroll
    for (int c = 0; c < GC; ++c) {
        #pragma unroll
        for (int off = 32; off > 0; off >>= 1) {
            float o = __shfl_xor(v[c], off, 64);
            v[c] = IS_MAX ? fmaxf(v[c], o) : v[c] + o;
        }
    }
    if (lane == 0) {
        #pragma unroll
        for (int c = 0; c < GC; ++c) s_red[c][wave] = v[c];
    }
    __syncthreads();
    #pragma unroll
    for (int c = 0; c < GC; ++c) {
        float r = s_red[c][0];
        #pragma unroll
        for (int w = 1; w < NWAVE; ++w)
            r = IS_MAX ? fmaxf(r, s_red[c][w]) : r + s_red[c][w];
        v[c] = r;
    }
    __syncthreads();
}

__global__ __launch_bounds__(NT) void nce_centre(
    const float* __restrict__ ws, const float* __restrict__ bgp,
    float* __restrict__ out)
{
    const int c0   = blockIdx.x * GC;
    const int tid  = threadIdx.x;
    const int wave = tid >> 6;
    const int lane = tid & 63;

    __shared__ float4 s_qi4[GC][DI/4];      // 256 B
    __shared__ float4 s_qe4[GC][DE/4];      // 1 KB
    __shared__ float  s_red[GC][NWAVE];     // 128 B
    __shared__ float4 s_w1p[NN];            // 16 KB  (4 centres packed per float4)
    __shared__ float4 s_w2p[NN];            // 16 KB
    __shared__ float  s_part[NWAVE][GC][DE];// 8 KB

    if (tid < GC*DI) ((float*)s_qi4)[tid] = ws[OFF_QI + c0*DI + tid];
    if (tid < GC*DE) ((float*)s_qe4)[tid] = ws[OFF_QE + c0*DE + tid];
    __syncthreads();

    const int nA = tid, nB = tid + NT;

    // ---------------- stage 1: a_i softmax ----------------
    float sA[GC], sB[GC];
    #pragma unroll
    for (int c = 0; c < GC; ++c) { sA[c] = 0.f; sB[c] = 0.f; }
    {
        const float4* kiA = (const float4*)(ws + OFF_KI + nA*DI);
        const float4* kiB = (const float4*)(ws + OFF_KI + nB*DI);
        #pragma unroll
        for (int q = 0; q < DI/4; ++q) {
            float4 a = kiA[q], b = kiB[q];
            #pragma unroll
            for (int c = 0; c < GC; ++c) {
                float4 qv = s_qi4[c][q];
                sA[c] += dot4(qv, a);
                sB[c] += dot4(qv, b);
            }
        }
    }
    float red[GC];
    #pragma unroll
    for (int c = 0; c < GC; ++c) {
        sA[c] *= 0.25f; sB[c] *= 0.25f;          // 1/sqrt(16)
        red[c] = fmaxf(sA[c], sB[c]);
    }
    blk_red<true>(red, s_red, wave, lane);
    float aiA[GC], aiB[GC];
    #pragma unroll
    for (int c = 0; c < GC; ++c) {
        aiA[c] = __expf(sA[c] - red[c]);
        aiB[c] = __expf(sB[c] - red[c]);
        red[c] = aiA[c] + aiB[c];
    }
    blk_red<false>(red, s_red, wave, lane);
    #pragma unroll
    for (int c = 0; c < GC; ++c) {
        float inv = 1.f / red[c];
        aiA[c] *= inv; aiB[c] *= inv;
    }

    // ---------------- stage 2: scores_e softmax + gate ----------------
    float s1A[GC], s2A[GC], s1B[GC], s2B[GC];
    #pragma unroll
    for (int c = 0; c < GC; ++c) { s1A[c]=0.f; s2A[c]=0.f; s1B[c]=0.f; s2B[c]=0.f; }
    {
        const float4* krA = (const float4*)(ws + OFF_KR + nA*DE);
        const float4* kvA = (const float4*)(ws + OFF_KV + nA*DE);
        const float4* krB = (const float4*)(ws + OFF_KR + nB*DE);
        const float4* kvB = (const float4*)(ws + OFF_KV + nB*DE);
        #pragma unroll
        for (int q = 0; q < DE/4; ++q) {
            float4 a = krA[q], b = kvA[q], e = krB[q], f = kvB[q];
            #pragma unroll
            for (int c = 0; c < GC; ++c) {
                float4 qv = s_qe4[c][q];
                s1A[c] += dot4(qv, a); s2A[c] += dot4(qv, b);
                s1B[c] += dot4(qv, e); s2B[c] += dot4(qv, f);
            }
        }
    }
    #pragma unroll
    for (int c = 0; c < GC; ++c) {
        sA[c] = (s1A[c] + aiA[c]*s2A[c]) * 0.125f;   // 1/sqrt(64)
        sB[c] = (s1B[c] + aiB[c]*s2B[c]) * 0.125f;
        red[c] = fmaxf(sA[c], sB[c]);
    }
    blk_red<true>(red, s_red, wave, lane);
    float eA[GC], eB[GC];
    #pragma unroll
    for (int c = 0; c < GC; ++c) {
        eA[c] = __expf(sA[c] - red[c]);
        eB[c] = __expf(sB[c] - red[c]);
        red[c] = eA[c] + eB[c];
    }
    blk_red<false>(red, s_red, wave, lane);

    const float bg  = *bgp;
    const float grA = ws[OFF_GR + nA], gvA = ws[OFF_GV + nA];
    const float grB = ws[OFF_GR + nB], gvB = ws[OFF_GV + nB];
    float w1A[GC], w2A[GC], w1B[GC], w2B[GC];
    #pragma unroll
    for (int c = 0; c < GC; ++c) {
        float inv = 1.f / red[c];
        float aeA = eA[c]*inv, aeB = eB[c]*inv;
        float preA = aeA*(grA + aiA[c]*gvA) + bg;
        float preB = aeB*(grB + aiB[c]*gvB) + bg;
        float gA = 1.f / (1.f + __expf(-preA));
        float gB = 1.f / (1.f + __expf(-preB));
        w1A[c] = gA*aeA; w2A[c] = w1A[c]*aiA[c];
        w1B[c] = gB*aeB; w2B[c] = w1B[c]*aiB[c];
    }
    s_w1p[nA] = make_float4(w1A[0], w1A[1], w1A[2], w1A[3]);
    s_w2p[nA] = make_float4(w2A[0], w2A[1], w2A[2], w2A[3]);
    s_w1p[nB] = make_float4(w1B[0], w1B[1], w1B[2], w1B[3]);
    s_w2p[nB] = make_float4(w2B[0], w2B[1], w2B[2], w2B[3]);
    __syncthreads();

    // ---------------- stage 3: out = w1@Vr + w2@Vv ----------------
    float acc[GC];
    #pragma unroll
    for (int c = 0; c < GC; ++c) acc[c] = 0.f;
    const int nbase = wave * (NN/NWAVE);          // 128 nodes per wave
    const float* vr = ws + OFF_VR + nbase*DE + lane;
    const float* vv = ws + OFF_VV + nbase*DE + lane;
    #pragma unroll 4
    for (int i = 0; i < NN/NWAVE; ++i) {
        const int n = nbase + i;
        float a = vr[i*DE];
        float b = vv[i*DE];
        float4 wa = s_w1p[n];
        float4 wb = s_w2p[n];
        acc[0] += wa.x*a + wb.x*b;  acc[1] += wa.y*a + wb.y*b;
        acc[2] += wa.z*a + wb.z*b;  acc[3] += wa.w*a + wb.w*b;
    }
    #pragma unroll
    for (int c = 0; c < GC; ++c) s_part[wave][c][lane] = acc[c];
    __syncthreads();
    if (tid < GC*DE) {
        const int c = tid >> 6;
        float r = 0.f;
        #pragma unroll
        for (int w = 0; w < NWAVE; ++w) r += s_part[w][c][lane];
        out[(c0 + c)*DE + lane] = r;
    }
}

extern "C" void kernel_launch(void* const* d_in, const int* in_sizes, int n_in,
                              void* d_out, int out_size, void* d_ws, size_t ws_size,
                              hipStream_t stream)
{
    const float* nc   = (const float*)d_in[0];
    const float* Wq_i = (const float*)d_in[1];
    const float* Wk_i = (const float*)d_in[2];
    const float* Wv_i = (const float*)d_in[3];
    const float* Wq_e = (const float*)d_in[4];
    const float* Wk_e = (const float*)d_in[5];
    const float* Wv_e = (const float*)d_in[6];
    const float* wg   = (const float*)d_in[7];
    const float* bg   = (const float*)d_in[8];
    float* out = (float*)d_out;
    float* ws  = (float*)d_ws;

    nce_precompute<<<NN/4, 256, 0, stream>>>(nc, Wq_i, Wk_i, Wv_i,
                                             Wq_e, Wk_e, Wv_e, wg, ws);
    nce_centre<<<NBLK, NT, 0, stream>>>(ws, bg, out);
}

// Round 4
// 38.096 us; speedup vs baseline: 1.4398x; 1.4398x over previous
//
#include <hip/hip_runtime.h>
#include <math.h>

#define NN 1024
#define DIN 6
#define DI 16
#define DE 64
#define GC 4              // centres per block
#define NT 512            // threads per centre-block
#define NWAVE (NT/64)     // 8
#define NBLK (NN/GC)      // 256

// ws layout (floats)
#define OFF_QI  0                        // [NN][DI]   node-major
#define OFF_KIT (OFF_QI + NN*DI)         // [DI][NN]   TRANSPOSED
#define OFF_QE  (OFF_KIT + NN*DI)        // [NN][DE]   node-major
#define OFF_KRV (OFF_QE + NN*DE)         // [DE][NN][2] (kr,kv) transposed+interleaved
#define OFF_VRV (OFF_KRV + NN*DE*2)      // [NN][DE][2] (vr,vv) interleaved
#define OFF_GR  (OFF_VRV + NN*DE*2)      // [NN]
#define OFF_GV  (OFF_GR + NN)            // [NN]

__device__ __forceinline__ float f4c(const float4& v, int i) {
    return i == 0 ? v.x : i == 1 ? v.y : i == 2 ? v.z : v.w;
}

__global__ __launch_bounds__(256) void nce_precompute(
    const float* __restrict__ nc,
    const float* __restrict__ Wq_i, const float* __restrict__ Wk_i,
    const float* __restrict__ Wv_i, const float* __restrict__ Wq_e,
    const float* __restrict__ Wk_e, const float* __restrict__ Wv_e,
    const float* __restrict__ wg, float* __restrict__ ws)
{
    const int s    = threadIdx.x >> 6;     // node sub-index within block
    const int lane = threadIdx.x & 63;     // = encoding dim d
    const int n    = blockIdx.x * 4 + s;
    __shared__ float s_vi[4][DI];

    float x[DIN];
    #pragma unroll
    for (int f = 0; f < DIN; ++f) x[f] = nc[n*DIN + f];

    if (lane < DI) {
        float qi = 0.f, ki = 0.f, vv = 0.f;
        #pragma unroll
        for (int f = 0; f < DIN; ++f) {
            qi += x[f] * Wq_i[f*DI + lane];
            ki += x[f] * Wk_i[f*DI + lane];
            vv += x[f] * Wv_i[f*DI + lane];
        }
        ws[OFF_QI + n*DI + lane] = qi;
        ws[OFF_KIT + lane*NN + n] = ki;      // transposed
        s_vi[s][lane] = vv;
    }
    __syncthreads();

    float qe = 0.f, kr = 0.f, vr = 0.f;
    #pragma unroll
    for (int f = 0; f < DIN; ++f) {
        qe += x[f] * Wq_e[f*DE + lane];
        kr += x[f] * Wk_e[f*DE + lane];
        vr += x[f] * Wv_e[f*DE + lane];
    }
    float kv = 0.f, vv2 = 0.f;
    #pragma unroll
    for (int j = 0; j < DI; ++j) {
        float v = s_vi[s][j];
        kv  += v * Wk_e[(DIN+j)*DE + lane];
        vv2 += v * Wv_e[(DIN+j)*DE + lane];
    }
    ws[OFF_QE + n*DE + lane] = qe;
    ((float2*)(ws + OFF_KRV))[lane*NN + n] = make_float2(kr, kv);   // transposed
    ((float2*)(ws + OFF_VRV))[n*DE + lane] = make_float2(vr, vv2);  // node-major

    float w   = wg[lane];
    float grt = vr * w, gvt = vv2 * w;
    #pragma unroll
    for (int off = 32; off > 0; off >>= 1) {
        grt += __shfl_xor(grt, off, 64);
        gvt += __shfl_xor(gvt, off, 64);
    }
    if (lane == 0) { ws[OFF_GR + n] = grt; ws[OFF_GV + n] = gvt; }
}

template<bool IS_MAX>
__device__ __forceinline__ void blk_red(float v[GC], float (*s_red)[NWAVE],
                                        int wave, int lane)
{
    #pragma unroll
    for (int c = 0; c < GC; ++c) {
        #pragma unroll
        for (int off = 32; off > 0; off >>= 1) {
            float o = __shfl_xor(v[c], off, 64);
            v[c] = IS_MAX ? fmaxf(v[c], o) : v[c] + o;
        }
    }
    if (lane == 0) {
        #pragma unroll
        for (int c = 0; c < GC; ++c) s_red[c][wave] = v[c];
    }
    __syncthreads();
    #pragma unroll
    for (int c = 0; c < GC; ++c) {
        float r = s_red[c][0];
        #pragma unroll
        for (int w = 1; w < NWAVE; ++w)
            r = IS_MAX ? fmaxf(r, s_red[c][w]) : r + s_red[c][w];
        v[c] = r;
    }
    __syncthreads();
}

__global__ __launch_bounds__(NT) void nce_centre(
    const float* __restrict__ ws, const float* __restrict__ bgp,
    float* __restrict__ out)
{
    const int c0   = blockIdx.x * GC;
    const int tid  = threadIdx.x;
    const int wave = tid >> 6;
    const int lane = tid & 63;

    __shared__ float4 s_qi4[GC][DI/4];      // 256 B
    __shared__ float4 s_qe4[GC][DE/4];      // 1 KB
    __shared__ float  s_red[GC][NWAVE];     // 128 B
    __shared__ float4 s_w1p[NN];            // 16 KB
    __shared__ float4 s_w2p[NN];            // 16 KB
    __shared__ float  s_part[NWAVE][GC][DE];// 8 KB

    if (tid < GC*DI) ((float*)s_qi4)[tid] = ws[OFF_QI + c0*DI + tid];
    if (tid < GC*DE) ((float*)s_qe4)[tid] = ws[OFF_QE + c0*DE + tid];
    __syncthreads();

    const int nA = tid, nB = tid + NT;

    // ---------------- stage 1: a_i softmax (coalesced KiT reads) ----------------
    float sA[GC], sB[GC];
    #pragma unroll
    for (int c = 0; c < GC; ++c) { sA[c] = 0.f; sB[c] = 0.f; }
    {
        const float* kit = ws + OFF_KIT;
        #pragma unroll
        for (int qb = 0; qb < DI/4; ++qb) {
            float4 qv[GC];
            #pragma unroll
            for (int c = 0; c < GC; ++c) qv[c] = s_qi4[c][qb];
            #pragma unroll
            for (int dd = 0; dd < 4; ++dd) {
                float ka = kit[(qb*4+dd)*NN + nA];
                float kb = kit[(qb*4+dd)*NN + nB];
                #pragma unroll
                for (int c = 0; c < GC; ++c) {
                    float q = f4c(qv[c], dd);
                    sA[c] += q * ka;
                    sB[c] += q * kb;
                }
            }
        }
    }
    float red[GC];
    #pragma unroll
    for (int c = 0; c < GC; ++c) {
        sA[c] *= 0.25f; sB[c] *= 0.25f;          // 1/sqrt(16)
        red[c] = fmaxf(sA[c], sB[c]);
    }
    blk_red<true>(red, s_red, wave, lane);
    float aiA[GC], aiB[GC];
    #pragma unroll
    for (int c = 0; c < GC; ++c) {
        aiA[c] = __expf(sA[c] - red[c]);
        aiB[c] = __expf(sB[c] - red[c]);
        red[c] = aiA[c] + aiB[c];
    }
    blk_red<false>(red, s_red, wave, lane);
    #pragma unroll
    for (int c = 0; c < GC; ++c) {
        float inv = 1.f / red[c];
        aiA[c] *= inv; aiB[c] *= inv;
    }

    // ------- stage 2: scores_e (coalesced KrKvT float2 reads), softmax + gate -------
    float s1A[GC], s2A[GC], s1B[GC], s2B[GC];
    #pragma unroll
    for (int c = 0; c < GC; ++c) { s1A[c]=0.f; s2A[c]=0.f; s1B[c]=0.f; s2B[c]=0.f; }
    {
        const float2* krv = (const float2*)(ws + OFF_KRV);
        #pragma unroll 4
        for (int qb = 0; qb < DE/4; ++qb) {
            float4 qv[GC];
            #pragma unroll
            for (int c = 0; c < GC; ++c) qv[c] = s_qe4[c][qb];
            #pragma unroll
            for (int dd = 0; dd < 4; ++dd) {
                const int d = qb*4 + dd;
                float2 a = krv[d*NN + nA];
                float2 b = krv[d*NN + nB];
                #pragma unroll
                for (int c = 0; c < GC; ++c) {
                    float q = f4c(qv[c], dd);
                    s1A[c] += q * a.x;  s2A[c] += q * a.y;
                    s1B[c] += q * b.x;  s2B[c] += q * b.y;
                }
            }
        }
    }
    #pragma unroll
    for (int c = 0; c < GC; ++c) {
        sA[c] = (s1A[c] + aiA[c]*s2A[c]) * 0.125f;   // 1/sqrt(64)
        sB[c] = (s1B[c] + aiB[c]*s2B[c]) * 0.125f;
        red[c] = fmaxf(sA[c], sB[c]);
    }
    blk_red<true>(red, s_red, wave, lane);
    float eA[GC], eB[GC];
    #pragma unroll
    for (int c = 0; c < GC; ++c) {
        eA[c] = __expf(sA[c] - red[c]);
        eB[c] = __expf(sB[c] - red[c]);
        red[c] = eA[c] + eB[c];
    }
    blk_red<false>(red, s_red, wave, lane);

    const float bg  = *bgp;
    const float grA = ws[OFF_GR + nA], gvA = ws[OFF_GV + nA];
    const float grB = ws[OFF_GR + nB], gvB = ws[OFF_GV + nB];
    float w1A[GC], w2A[GC], w1B[GC], w2B[GC];
    #pragma unroll
    for (int c = 0; c < GC; ++c) {
        float inv = 1.f / red[c];
        float aeA = eA[c]*inv, aeB = eB[c]*inv;
        float preA = aeA*(grA + aiA[c]*gvA) + bg;
        float preB = aeB*(grB + aiB[c]*gvB) + bg;
        float gA = 1.f / (1.f + __expf(-preA));
        float gB = 1.f / (1.f + __expf(-preB));
        w1A[c] = gA*aeA; w2A[c] = w1A[c]*aiA[c];
        w1B[c] = gB*aeB; w2B[c] = w1B[c]*aiB[c];
    }
    s_w1p[nA] = make_float4(w1A[0], w1A[1], w1A[2], w1A[3]);
    s_w2p[nA] = make_float4(w2A[0], w2A[1], w2A[2], w2A[3]);
    s_w1p[nB] = make_float4(w1B[0], w1B[1], w1B[2], w1B[3]);
    s_w2p[nB] = make_float4(w2B[0], w2B[1], w2B[2], w2B[3]);
    __syncthreads();

    // ---------------- stage 3: out = w1@Vr + w2@Vv (float2 interleaved) ----------------
    float acc[GC];
    #pragma unroll
    for (int c = 0; c < GC; ++c) acc[c] = 0.f;
    const int nbase = wave * (NN/NWAVE);          // 128 nodes per wave
    const float2* vrv = (const float2*)(ws + OFF_VRV) + nbase*DE + lane;
    #pragma unroll 8
    for (int i = 0; i < NN/NWAVE; ++i) {
        const int n = nbase + i;
        float2 v = vrv[i*DE];
        float4 wa = s_w1p[n];
        float4 wb = s_w2p[n];
        acc[0] += wa.x*v.x + wb.x*v.y;  acc[1] += wa.y*v.x + wb.y*v.y;
        acc[2] += wa.z*v.x + wb.z*v.y;  acc[3] += wa.w*v.x + wb.w*v.y;
    }
    #pragma unroll
    for (int c = 0; c < GC; ++c) s_part[wave][c][lane] = acc[c];
    __syncthreads();
    if (tid < GC*DE) {
        const int c = tid >> 6;
        float r = 0.f;
        #pragma unroll
        for (int w = 0; w < NWAVE; ++w) r += s_part[w][c][lane];
        out[(c0 + c)*DE + lane] = r;
    }
}

extern "C" void kernel_launch(void* const* d_in, const int* in_sizes, int n_in,
                              void* d_out, int out_size, void* d_ws, size_t ws_size,
                              hipStream_t stream)
{
    const float* nc   = (const float*)d_in[0];
    const float* Wq_i = (const float*)d_in[1];
    const float* Wk_i = (const float*)d_in[2];
    const float* Wv_i = (const float*)d_in[3];
    const float* Wq_e = (const float*)d_in[4];
    const float* Wk_e = (const float*)d_in[5];
    const float* Wv_e = (const float*)d_in[6];
    const float* wg   = (const float*)d_in[7];
    const float* bg   = (const float*)d_in[8];
    float* out = (float*)d_out;
    float* ws  = (float*)d_ws;

    nce_precompute<<<NN/4, 256, 0, stream>>>(nc, Wq_i, Wk_i, Wv_i,
                                             Wq_e, Wk_e, Wv_e, wg, ws);
    nce_centre<<<NBLK, NT, 0, stream>>>(ws, bg, out);
}